// Round 8
// baseline (466.387 us; speedup 1.0000x reference)
//
#include <hip/hip_runtime.h>

// ---------------------------------------------------------------------------
// DoubleLayeredEncoder: 2-layer GCN + PReLU + half-sum. N=100k, E=1.6M.
// R8: revert to R4 single-pass ELL (measured floor ~114us, random-line-touch
// bound at ~28G touches/s). De-fuse gemm2 (inline version cost ~2 VALU/MAC;
// clean register-blocked kernel + 51MB streaming is cheaper). Counting-sort
// nodes by ELL length (replicated bins, no hot atomics) so the 4 nodes in
// each gather wave have equal len -> subgroup divergence ~0 (was ~29% waste).
//
// Pipeline: memset -> gemm1 -> ell -> dinv(+len,+rank) -> offs -> place
//           -> g1(sorted) -> gemm2b -> g2(sorted) -> half
// ---------------------------------------------------------------------------

#define ELL_CAP 64
#define NREP 32   // replicated bin rows for rank atomics

__device__ __forceinline__ unsigned bf16rne(float x) {
    unsigned u = __float_as_uint(x);
    return (u + 0x7FFFu + ((u >> 16) & 1u)) >> 16;
}
__device__ __forceinline__ unsigned pack2bf(float a, float b) {
    return bf16rne(a) | (bf16rne(b) << 16);
}
__device__ __forceinline__ float bflo(unsigned u) { return __uint_as_float(u << 16); }
__device__ __forceinline__ float bfhi(unsigned u) { return __uint_as_float(u & 0xFFFF0000u); }

// ---- ELL build: 1 edge/thread (R4 form) ------------------------------------
__global__ __launch_bounds__(256) void k_ell(const int* __restrict__ src,
                                             const int* __restrict__ dst,
                                             const int* __restrict__ et,
                                             const float* __restrict__ w,
                                             int* __restrict__ cnt,
                                             int2* __restrict__ ell, int E) {
    int e = blockIdx.x * 256 + threadIdx.x;
    if (e >= E) return;
    int d = dst[e];
    int pos = atomicAdd(&cnt[d], 1);
    if (pos < ELL_CAP)
        ell[(size_t)d * ELL_CAP + pos] =
            make_int2(src[e] | (et[e] << 24), __float_as_int(w[e]));
}

// ---- degrees + rsqrt + len + sort-rank, 16 lanes/node ----------------------
__global__ __launch_bounds__(256) void k_dinv(const int* __restrict__ cnt,
                                              const int2* __restrict__ ell,
                                              float* __restrict__ dinv1,
                                              float* __restrict__ dinv2,
                                              int* __restrict__ lens,
                                              int* __restrict__ rank1,
                                              int* __restrict__ nbin, int n) {
    int t = threadIdx.x;
    int d = blockIdx.x * 16 + (t >> 4);
    int g = t & 15;
    float s1 = 0.f, s2 = 0.f;
    int len = 0;
    if (d < n) {
        len = min(cnt[d], ELL_CAP);
        const int2* row = ell + (size_t)d * ELL_CAP;
        for (int kk = g; kk < len; kk += 16) {
            int2 e = row[kk];
            s1 += __int_as_float(e.y);
            s2 += (float)(((unsigned)e.x) >> 24);
        }
    }
#pragma unroll
    for (int o = 8; o >= 1; o >>= 1) {
        s1 += __shfl_xor(s1, o, 16);
        s2 += __shfl_xor(s2, o, 16);
    }
    if (d < n && g == 0) {
        dinv1[d] = rsqrtf(1.0f + s1);
        dinv2[d] = rsqrtf(1.0f + s2);
        lens[d] = len;
        rank1[d] = atomicAdd(&nbin[((d >> 4) & (NREP - 1)) * 65 + len], 1);
    }
}

// ---- bins -> global offsets (single block) ---------------------------------
__global__ __launch_bounds__(256) void k_offs(int* __restrict__ nbin) {
    __shared__ int tot[65];
    __shared__ int base[65];
    int t = threadIdx.x;
    if (t < 65) {
        int s = 0;
        for (int r = 0; r < NREP; r++) s += nbin[r * 65 + t];
        tot[t] = s;
    }
    __syncthreads();
    if (t == 0) {
        int a = 0;
        for (int l = 0; l < 65; l++) { base[l] = a; a += tot[l]; }
    }
    __syncthreads();
    if (t < 65) {
        int a = base[t];
        for (int r = 0; r < NREP; r++) {
            int c = nbin[r * 65 + t];
            nbin[r * 65 + t] = a;
            a += c;
        }
    }
}

__global__ __launch_bounds__(256) void k_place(const int* __restrict__ lens,
                                               const int* __restrict__ rank1,
                                               const int* __restrict__ nbin,
                                               int* __restrict__ order, int n) {
    int d = blockIdx.x * 256 + threadIdx.x;
    if (d >= n) return;
    order[nbin[((d >> 4) & (NREP - 1)) * 65 + lens[d]] + rank1[d]] = d;
}

// ---- gemm1: xb1 = bf16(x @ W1) UNSCALED. 32 rows/block, W from L2 ----------
__global__ __launch_bounds__(256) void k_gemm1(const float* __restrict__ x,
                                               const float* __restrict__ W,
                                               unsigned* __restrict__ xb1, int n) {
    __shared__ float xs[128 * 32];   // [k][r], lane-fast row map (conflict-free)
    int t = threadIdx.x;
    int row0 = blockIdx.x * 32;
    const float4* x4 = (const float4*)x;
#pragma unroll
    for (int i = 0; i < 4; i++) {
        int q = t + 256 * i;
        int r = q & 31;
        int c4 = (q >> 5) << 2;
        int row = row0 + r;
        float4 v = make_float4(0.f, 0.f, 0.f, 0.f);
        if (row < n) v = x4[row * 32 + (c4 >> 2)];
        xs[(c4 + 0) * 32 + r] = v.x;
        xs[(c4 + 1) * 32 + r] = v.y;
        xs[(c4 + 2) * 32 + r] = v.z;
        xs[(c4 + 3) * 32 + r] = v.w;
    }
    __syncthreads();

    int c4 = (t & 31) << 2;
    int r4 = (t >> 5) << 2;
    const float4* W4 = (const float4*)W;
    float acc[4][4] = {};
#pragma unroll 8
    for (int k = 0; k < 128; k++) {
        float4 xv = *(const float4*)&xs[k * 32 + r4];
        float4 wv = W4[k * 32 + (c4 >> 2)];
        acc[0][0] += xv.x * wv.x; acc[0][1] += xv.x * wv.y; acc[0][2] += xv.x * wv.z; acc[0][3] += xv.x * wv.w;
        acc[1][0] += xv.y * wv.x; acc[1][1] += xv.y * wv.y; acc[1][2] += xv.y * wv.z; acc[1][3] += xv.y * wv.w;
        acc[2][0] += xv.z * wv.x; acc[2][1] += xv.z * wv.y; acc[2][2] += xv.z * wv.z; acc[2][3] += xv.z * wv.w;
        acc[3][0] += xv.w * wv.x; acc[3][1] += xv.w * wv.y; acc[3][2] += xv.w * wv.z; acc[3][3] += xv.w * wv.w;
    }
#pragma unroll
    for (int i = 0; i < 4; i++) {
        int row = row0 + r4 + i;
        if (row < n) {
            uint2 o = make_uint2(pack2bf(acc[i][0], acc[i][1]),
                                 pack2bf(acc[i][2], acc[i][3]));
            ((uint2*)xb1)[row * 32 + (c4 >> 2)] = o;
        }
    }
}

// ---- gather1 (+dinv, bias, PReLU) -> h1 bf16. 16 lanes x 8ch, len-sorted ---
__global__ __launch_bounds__(256) void k_g1(const int* __restrict__ order,
                                            const int* __restrict__ lens,
                                            const int2* __restrict__ ell,
                                            const unsigned* __restrict__ xb1,
                                            const float* __restrict__ dinv1,
                                            const float* __restrict__ b,
                                            const float* __restrict__ alpha,
                                            unsigned* __restrict__ h1b, int n) {
    int t = threadIdx.x;
    int i = blockIdx.x * 16 + (t >> 4);
    if (i >= n) return;
    int g = t & 15;
    int d = order[i];
    int len = lens[d];
    const int2* row = ell + (size_t)d * ELL_CAP;
    const uint4* x4 = (const uint4*)xb1;

    float a0 = 0.f, a1 = 0.f, a2 = 0.f, a3 = 0.f;
    float a4 = 0.f, a5 = 0.f, a6 = 0.f, a7 = 0.f;
    for (int k0 = 0; k0 < len; k0 += 16) {
        int kk = k0 + g;
        int2 ent = make_int2(0, 0);
        float cf = 0.f;
        if (kk < len) {
            ent = row[kk];
            cf = __int_as_float(ent.y) * dinv1[ent.x & 0xFFFFFF];   // w*dinv1[src]
        }
        int m = min(16, len - k0);
        for (int j = 0; j < m; j++) {
            int pej = __shfl(ent.x, j, 16);
            float cj = __shfl(cf, j, 16);
            uint4 q = x4[(size_t)(pej & 0xFFFFFF) * 16 + g];
            a0 += bflo(q.x) * cj; a1 += bfhi(q.x) * cj;
            a2 += bflo(q.y) * cj; a3 += bfhi(q.y) * cj;
            a4 += bflo(q.z) * cj; a5 += bfhi(q.z) * cj;
            a6 += bflo(q.w) * cj; a7 += bfhi(q.w) * cj;
        }
    }

    float di = dinv1[d];
    uint4 sq = x4[(size_t)d * 16 + g];
    int c8 = g << 3;
    float4 blo = *(const float4*)&b[c8], bhi = *(const float4*)&b[c8 + 4];
    float4 alo = *(const float4*)&alpha[c8], ahi = *(const float4*)&alpha[c8 + 4];
    float v0 = di * (a0 + bflo(sq.x) * di) + blo.x; v0 = v0 >= 0.f ? v0 : alo.x * v0;
    float v1 = di * (a1 + bfhi(sq.x) * di) + blo.y; v1 = v1 >= 0.f ? v1 : alo.y * v1;
    float v2 = di * (a2 + bflo(sq.y) * di) + blo.z; v2 = v2 >= 0.f ? v2 : alo.z * v2;
    float v3 = di * (a3 + bfhi(sq.y) * di) + blo.w; v3 = v3 >= 0.f ? v3 : alo.w * v3;
    float v4 = di * (a4 + bflo(sq.z) * di) + bhi.x; v4 = v4 >= 0.f ? v4 : ahi.x * v4;
    float v5 = di * (a5 + bfhi(sq.z) * di) + bhi.y; v5 = v5 >= 0.f ? v5 : ahi.y * v5;
    float v6 = di * (a6 + bflo(sq.w) * di) + bhi.z; v6 = v6 >= 0.f ? v6 : ahi.z * v6;
    float v7 = di * (a7 + bfhi(sq.w) * di) + bhi.w; v7 = v7 >= 0.f ? v7 : ahi.w * v7;
    ((uint4*)h1b)[(size_t)d * 16 + g] =
        make_uint4(pack2bf(v0, v1), pack2bf(v2, v3), pack2bf(v4, v5), pack2bf(v6, v7));
}

// ---- gemm2b: xb2 = bf16(h1b @ W2) UNSCALED. 32 rows/block, 2x4 acc ---------
__global__ __launch_bounds__(256) void k_gemm2b(const unsigned* __restrict__ h1b,
                                                const float* __restrict__ W2,
                                                unsigned* __restrict__ xb2, int n) {
    __shared__ float xs[128 * 32];   // [k][r], 16 KB
    int t = threadIdx.x;
    int row0 = blockIdx.x * 32;
    const uint2* h2 = (const uint2*)h1b;   // row = 32 uint2 (128 bf16)
#pragma unroll
    for (int i = 0; i < 4; i++) {
        int q = t + 256 * i;         // 0..1023 = 32 rows x 32 uint2-cols
        int r = q & 31;
        int c2 = q >> 5;
        int row = row0 + r;
        uint2 v = make_uint2(0u, 0u);
        if (row < n) v = h2[(size_t)row * 32 + c2];
        int c = c2 << 2;
        xs[(c + 0) * 32 + r] = bflo(v.x);
        xs[(c + 1) * 32 + r] = bfhi(v.x);
        xs[(c + 2) * 32 + r] = bflo(v.y);
        xs[(c + 3) * 32 + r] = bfhi(v.y);
    }
    __syncthreads();

    int c4 = (t & 15) << 2;          // out col 0..60
    int r2 = (t >> 4) << 1;          // out row pair 0..30
    const float4* W4 = (const float4*)W2;   // row = 16 float4
    float acc[2][4] = {};
#pragma unroll 8
    for (int k = 0; k < 128; k++) {
        float2 xv = *(const float2*)&xs[k * 32 + r2];
        float4 wv = W4[k * 16 + (c4 >> 2)];
        acc[0][0] += xv.x * wv.x; acc[0][1] += xv.x * wv.y; acc[0][2] += xv.x * wv.z; acc[0][3] += xv.x * wv.w;
        acc[1][0] += xv.y * wv.x; acc[1][1] += xv.y * wv.y; acc[1][2] += xv.y * wv.z; acc[1][3] += xv.y * wv.w;
    }
#pragma unroll
    for (int i = 0; i < 2; i++) {
        int row = row0 + r2 + i;
        if (row < n)
            ((uint2*)xb2)[(size_t)row * 16 + (c4 >> 2)] =
                make_uint2(pack2bf(acc[i][0], acc[i][1]), pack2bf(acc[i][2], acc[i][3]));
    }
}

// ---- gather2 (+dinv, bias, PReLU) -> f fp32. len-sorted, skip etype==0 -----
__global__ __launch_bounds__(256) void k_g2(const int* __restrict__ order,
                                            const int* __restrict__ lens,
                                            const int2* __restrict__ ell,
                                            const unsigned* __restrict__ xb2,
                                            const float* __restrict__ dinv2,
                                            const float* __restrict__ b,
                                            const float* __restrict__ alpha,
                                            float* __restrict__ f, int n) {
    int t = threadIdx.x;
    int i = blockIdx.x * 16 + (t >> 4);
    if (i >= n) return;
    int g = t & 15;
    int d = order[i];
    int len = lens[d];
    const int2* row = ell + (size_t)d * ELL_CAP;
    const uint2* x2 = (const uint2*)xb2;

    float a0 = 0.f, a1 = 0.f, a2 = 0.f, a3 = 0.f;
    for (int k0 = 0; k0 < len; k0 += 16) {
        int kk = k0 + g;
        int2 ent = make_int2(0, 0);
        float cf = 0.f;
        if (kk < len) {
            ent = row[kk];
            int tt = ((unsigned)ent.x) >> 24;
            if (tt) cf = (float)tt * dinv2[ent.x & 0xFFFFFF];   // et*dinv2[src]
        }
        int m = min(16, len - k0);
        for (int j = 0; j < m; j++) {
            int pej = __shfl(ent.x, j, 16);
            float cj = __shfl(cf, j, 16);
            if (cj != 0.f) {
                uint2 q = x2[(size_t)(pej & 0xFFFFFF) * 16 + g];
                a0 += bflo(q.x) * cj; a1 += bfhi(q.x) * cj;
                a2 += bflo(q.y) * cj; a3 += bfhi(q.y) * cj;
            }
        }
    }

    float di = dinv2[d];
    uint2 sq = x2[(size_t)d * 16 + g];
    int c4 = g << 2;
    float4 bv = *(const float4*)&b[c4];
    float4 av = *(const float4*)&alpha[c4];
    float f0 = di * (a0 + bflo(sq.x) * di) + bv.x; f0 = f0 >= 0.f ? f0 : av.x * f0;
    float f1 = di * (a1 + bfhi(sq.x) * di) + bv.y; f1 = f1 >= 0.f ? f1 : av.y * f1;
    float f2 = di * (a2 + bflo(sq.y) * di) + bv.z; f2 = f2 >= 0.f ? f2 : av.z * f2;
    float f3 = di * (a3 + bfhi(sq.y) * di) + bv.w; f3 = f3 >= 0.f ? f3 : av.w * f3;
    ((float4*)f)[(size_t)d * 16 + g] = make_float4(f0, f1, f2, f3);
}

__global__ __launch_bounds__(256) void k_half(const float* __restrict__ f,
                                              float* __restrict__ out, int half) {
    int idx = blockIdx.x * 256 + threadIdx.x;   // over half*16 float4s
    if (idx >= half * 16) return;
    int j = idx >> 4;
    int g = idx & 15;
    float4 a = ((const float4*)f)[(size_t)j * 16 + g];
    float4 c = ((const float4*)f)[(size_t)(j + half) * 16 + g];
    ((float4*)out)[idx] = make_float4(0.5f * (a.x + c.x), 0.5f * (a.y + c.y),
                                      0.5f * (a.z + c.z), 0.5f * (a.w + c.w));
}

extern "C" void kernel_launch(void* const* d_in, const int* in_sizes, int n_in,
                              void* d_out, int out_size, void* d_ws, size_t ws_size,
                              hipStream_t stream) {
    const float* x  = (const float*)d_in[0];
    const int*   ei = (const int*)d_in[1];
    const float* ew = (const float*)d_in[2];
    const int*   et = (const int*)d_in[3];
    const float* W1 = (const float*)d_in[4];
    const float* b1 = (const float*)d_in[5];
    const float* a1 = (const float*)d_in[6];
    const float* W2 = (const float*)d_in[7];
    const float* b2 = (const float*)d_in[8];
    const float* a2 = (const float*)d_in[9];

    const int N = in_sizes[0] / 128;   // 100000
    const int E = in_sizes[1] / 2;     // 1600000
    const int* src = ei;
    const int* dst = ei + E;

    // Workspace (4-byte words), ~118 MB:
    //   dinv1 N | dinv2 N | lens N | rank1 N | order1 N | cnt N | nbin 2080 |
    //   xb1 64N | h1b 64N | xb2 32N | ell 128N.   f aliases xb1 (dead after g1).
    float*    ws    = (float*)d_ws;
    float*    dinv1 = ws;
    float*    dinv2 = dinv1 + N;
    int*      lens  = (int*)(dinv2 + N);
    int*      rank1 = lens + N;
    int*      order = rank1 + N;
    int*      cnt   = order + N;
    int*      nbin  = cnt + N;                    // NREP*65 = 2080 ints
    unsigned* xb1   = (unsigned*)(nbin + NREP * 65);
    unsigned* h1b   = xb1 + (size_t)N * 64;
    unsigned* xb2   = h1b + (size_t)N * 64;
    int2*     ell   = (int2*)(xb2 + (size_t)N * 32);
    float*    f     = (float*)xb1;                // xb1 dead after k_g1

    const int half = N / 2;

    hipMemsetAsync(cnt, 0, ((size_t)N + NREP * 65) * sizeof(int), stream);

    k_gemm1<<<(N + 31) / 32, 256, 0, stream>>>(x, W1, xb1, N);

    k_ell<<<(E + 255) / 256, 256, 0, stream>>>(src, dst, et, ew, cnt, ell, E);

    k_dinv<<<(N + 15) / 16, 256, 0, stream>>>(cnt, ell, dinv1, dinv2,
                                              lens, rank1, nbin, N);
    k_offs<<<1, 256, 0, stream>>>(nbin);
    k_place<<<(N + 255) / 256, 256, 0, stream>>>(lens, rank1, nbin, order, N);

    k_g1<<<(N + 15) / 16, 256, 0, stream>>>(order, lens, ell, xb1, dinv1,
                                            b1, a1, h1b, N);

    k_gemm2b<<<(N + 31) / 32, 256, 0, stream>>>(h1b, W2, xb2, N);

    k_g2<<<(N + 15) / 16, 256, 0, stream>>>(order, lens, ell, xb2, dinv2,
                                            b2, a2, f, N);

    k_half<<<(half * 16 + 255) / 256, 256, 0, stream>>>(f, (float*)d_out, half);
}

// Round 9
// 457.118 us; speedup vs baseline: 1.0203x; 1.0203x over previous
//
#include <hip/hip_runtime.h>

// ---------------------------------------------------------------------------
// DoubleLayeredEncoder: 2-layer GCN + PReLU + half-sum. N=100k, E=1.6M.
// R9: fixed-trip-count (16) fully-unrolled gather inner loop with zero-padded
// entries -> compiler can issue all 16 row-loads of a chunk concurrently
// (was a serial dependent chain: shfl -> dinv gather -> row load, ~1
// outstanding load/wave). g2 drops the divergent etype==0 skip (always-load;
// xb2 is 12.8 MB, cache-resident). Len-sort kept (uniform chunk counts in
// each wave). ELL build kept at its measured random-line-touch floor.
//
// Pipeline: memset -> gemm1 -> ell -> dinv(+len,+rank) -> offs -> place
//           -> g1(sorted) -> gemm2b -> g2(sorted) -> half
// ---------------------------------------------------------------------------

#define ELL_CAP 64
#define NREP 32   // replicated bin rows for rank atomics

__device__ __forceinline__ unsigned bf16rne(float x) {
    unsigned u = __float_as_uint(x);
    return (u + 0x7FFFu + ((u >> 16) & 1u)) >> 16;
}
__device__ __forceinline__ unsigned pack2bf(float a, float b) {
    return bf16rne(a) | (bf16rne(b) << 16);
}
__device__ __forceinline__ float bflo(unsigned u) { return __uint_as_float(u << 16); }
__device__ __forceinline__ float bfhi(unsigned u) { return __uint_as_float(u & 0xFFFF0000u); }

// ---- ELL build: 1 edge/thread --------------------------------------------
__global__ __launch_bounds__(256) void k_ell(const int* __restrict__ src,
                                             const int* __restrict__ dst,
                                             const int* __restrict__ et,
                                             const float* __restrict__ w,
                                             int* __restrict__ cnt,
                                             int2* __restrict__ ell, int E) {
    int e = blockIdx.x * 256 + threadIdx.x;
    if (e >= E) return;
    int d = dst[e];
    int pos = atomicAdd(&cnt[d], 1);
    if (pos < ELL_CAP)
        ell[(size_t)d * ELL_CAP + pos] =
            make_int2(src[e] | (et[e] << 24), __float_as_int(w[e]));
}

// ---- degrees + rsqrt + len + sort-rank, 16 lanes/node ----------------------
__global__ __launch_bounds__(256) void k_dinv(const int* __restrict__ cnt,
                                              const int2* __restrict__ ell,
                                              float* __restrict__ dinv1,
                                              float* __restrict__ dinv2,
                                              int* __restrict__ lens,
                                              int* __restrict__ rank1,
                                              int* __restrict__ nbin, int n) {
    int t = threadIdx.x;
    int d = blockIdx.x * 16 + (t >> 4);
    int g = t & 15;
    float s1 = 0.f, s2 = 0.f;
    int len = 0;
    if (d < n) {
        len = min(cnt[d], ELL_CAP);
        const int2* row = ell + (size_t)d * ELL_CAP;
        for (int kk = g; kk < len; kk += 16) {
            int2 e = row[kk];
            s1 += __int_as_float(e.y);
            s2 += (float)(((unsigned)e.x) >> 24);
        }
    }
#pragma unroll
    for (int o = 8; o >= 1; o >>= 1) {
        s1 += __shfl_xor(s1, o, 16);
        s2 += __shfl_xor(s2, o, 16);
    }
    if (d < n && g == 0) {
        dinv1[d] = rsqrtf(1.0f + s1);
        dinv2[d] = rsqrtf(1.0f + s2);
        lens[d] = len;
        rank1[d] = atomicAdd(&nbin[((d >> 4) & (NREP - 1)) * 65 + len], 1);
    }
}

// ---- bins -> global offsets (single block) ---------------------------------
__global__ __launch_bounds__(256) void k_offs(int* __restrict__ nbin) {
    __shared__ int tot[65];
    __shared__ int base[65];
    int t = threadIdx.x;
    if (t < 65) {
        int s = 0;
        for (int r = 0; r < NREP; r++) s += nbin[r * 65 + t];
        tot[t] = s;
    }
    __syncthreads();
    if (t == 0) {
        int a = 0;
        for (int l = 0; l < 65; l++) { base[l] = a; a += tot[l]; }
    }
    __syncthreads();
    if (t < 65) {
        int a = base[t];
        for (int r = 0; r < NREP; r++) {
            int c = nbin[r * 65 + t];
            nbin[r * 65 + t] = a;
            a += c;
        }
    }
}

__global__ __launch_bounds__(256) void k_place(const int* __restrict__ lens,
                                               const int* __restrict__ rank1,
                                               const int* __restrict__ nbin,
                                               int* __restrict__ order, int n) {
    int d = blockIdx.x * 256 + threadIdx.x;
    if (d >= n) return;
    order[nbin[((d >> 4) & (NREP - 1)) * 65 + lens[d]] + rank1[d]] = d;
}

// ---- gemm1: xb1 = bf16(x @ W1) UNSCALED. 32 rows/block, W from L2 ----------
__global__ __launch_bounds__(256) void k_gemm1(const float* __restrict__ x,
                                               const float* __restrict__ W,
                                               unsigned* __restrict__ xb1, int n) {
    __shared__ float xs[128 * 32];   // [k][r], lane-fast row map (conflict-free)
    int t = threadIdx.x;
    int row0 = blockIdx.x * 32;
    const float4* x4 = (const float4*)x;
#pragma unroll
    for (int i = 0; i < 4; i++) {
        int q = t + 256 * i;
        int r = q & 31;
        int c4 = (q >> 5) << 2;
        int row = row0 + r;
        float4 v = make_float4(0.f, 0.f, 0.f, 0.f);
        if (row < n) v = x4[row * 32 + (c4 >> 2)];
        xs[(c4 + 0) * 32 + r] = v.x;
        xs[(c4 + 1) * 32 + r] = v.y;
        xs[(c4 + 2) * 32 + r] = v.z;
        xs[(c4 + 3) * 32 + r] = v.w;
    }
    __syncthreads();

    int c4 = (t & 31) << 2;
    int r4 = (t >> 5) << 2;
    const float4* W4 = (const float4*)W;
    float acc[4][4] = {};
#pragma unroll 8
    for (int k = 0; k < 128; k++) {
        float4 xv = *(const float4*)&xs[k * 32 + r4];
        float4 wv = W4[k * 32 + (c4 >> 2)];
        acc[0][0] += xv.x * wv.x; acc[0][1] += xv.x * wv.y; acc[0][2] += xv.x * wv.z; acc[0][3] += xv.x * wv.w;
        acc[1][0] += xv.y * wv.x; acc[1][1] += xv.y * wv.y; acc[1][2] += xv.y * wv.z; acc[1][3] += xv.y * wv.w;
        acc[2][0] += xv.z * wv.x; acc[2][1] += xv.z * wv.y; acc[2][2] += xv.z * wv.z; acc[2][3] += xv.z * wv.w;
        acc[3][0] += xv.w * wv.x; acc[3][1] += xv.w * wv.y; acc[3][2] += xv.w * wv.z; acc[3][3] += xv.w * wv.w;
    }
#pragma unroll
    for (int i = 0; i < 4; i++) {
        int row = row0 + r4 + i;
        if (row < n) {
            uint2 o = make_uint2(pack2bf(acc[i][0], acc[i][1]),
                                 pack2bf(acc[i][2], acc[i][3]));
            ((uint2*)xb1)[row * 32 + (c4 >> 2)] = o;
        }
    }
}

// ---- gather1 (+dinv, bias, PReLU) -> h1 bf16. 16 lanes x 8ch ---------------
// Fixed 16-iteration unrolled chunk: 16 concurrent row loads per wave.
__global__ __launch_bounds__(256) void k_g1(const int* __restrict__ order,
                                            const int* __restrict__ lens,
                                            const int2* __restrict__ ell,
                                            const unsigned* __restrict__ xb1,
                                            const float* __restrict__ dinv1,
                                            const float* __restrict__ b,
                                            const float* __restrict__ alpha,
                                            unsigned* __restrict__ h1b, int n) {
    int t = threadIdx.x;
    int i = blockIdx.x * 16 + (t >> 4);
    if (i >= n) return;
    int g = t & 15;
    int d = order[i];
    int len = lens[d];
    const int2* row = ell + (size_t)d * ELL_CAP;
    const uint4* x4 = (const uint4*)xb1;

    float a0 = 0.f, a1 = 0.f, a2 = 0.f, a3 = 0.f;
    float a4 = 0.f, a5 = 0.f, a6 = 0.f, a7 = 0.f;
    for (int k0 = 0; k0 < len; k0 += 16) {
        int kk = k0 + g;
        int2 ent = make_int2(0, 0);
        float cf = 0.f;
        if (kk < len) {
            ent = row[kk];
            cf = __int_as_float(ent.y) * dinv1[ent.x & 0xFFFFFF];   // w*dinv1[src]
        }
#pragma unroll
        for (int j = 0; j < 16; j++) {
            int pej = __shfl(ent.x, j, 16);
            float cj = __shfl(cf, j, 16);
            uint4 q = x4[(size_t)(pej & 0xFFFFFF) * 16 + g];  // pad -> row 0, cj=0
            a0 += bflo(q.x) * cj; a1 += bfhi(q.x) * cj;
            a2 += bflo(q.y) * cj; a3 += bfhi(q.y) * cj;
            a4 += bflo(q.z) * cj; a5 += bfhi(q.z) * cj;
            a6 += bflo(q.w) * cj; a7 += bfhi(q.w) * cj;
        }
    }

    float di = dinv1[d];
    uint4 sq = x4[(size_t)d * 16 + g];
    int c8 = g << 3;
    float4 blo = *(const float4*)&b[c8], bhi = *(const float4*)&b[c8 + 4];
    float4 alo = *(const float4*)&alpha[c8], ahi = *(const float4*)&alpha[c8 + 4];
    float v0 = di * (a0 + bflo(sq.x) * di) + blo.x; v0 = v0 >= 0.f ? v0 : alo.x * v0;
    float v1 = di * (a1 + bfhi(sq.x) * di) + blo.y; v1 = v1 >= 0.f ? v1 : alo.y * v1;
    float v2 = di * (a2 + bflo(sq.y) * di) + blo.z; v2 = v2 >= 0.f ? v2 : alo.z * v2;
    float v3 = di * (a3 + bfhi(sq.y) * di) + blo.w; v3 = v3 >= 0.f ? v3 : alo.w * v3;
    float v4 = di * (a4 + bflo(sq.z) * di) + bhi.x; v4 = v4 >= 0.f ? v4 : ahi.x * v4;
    float v5 = di * (a5 + bfhi(sq.z) * di) + bhi.y; v5 = v5 >= 0.f ? v5 : ahi.y * v5;
    float v6 = di * (a6 + bflo(sq.w) * di) + bhi.z; v6 = v6 >= 0.f ? v6 : ahi.z * v6;
    float v7 = di * (a7 + bfhi(sq.w) * di) + bhi.w; v7 = v7 >= 0.f ? v7 : ahi.w * v7;
    ((uint4*)h1b)[(size_t)d * 16 + g] =
        make_uint4(pack2bf(v0, v1), pack2bf(v2, v3), pack2bf(v4, v5), pack2bf(v6, v7));
}

// ---- gemm2b: xb2 = bf16(h1b @ W2) UNSCALED. 32 rows/block, 2x4 acc ---------
__global__ __launch_bounds__(256) void k_gemm2b(const unsigned* __restrict__ h1b,
                                                const float* __restrict__ W2,
                                                unsigned* __restrict__ xb2, int n) {
    __shared__ float xs[128 * 32];   // [k][r], 16 KB
    int t = threadIdx.x;
    int row0 = blockIdx.x * 32;
    const uint2* h2 = (const uint2*)h1b;   // row = 32 uint2 (128 bf16)
#pragma unroll
    for (int i = 0; i < 4; i++) {
        int q = t + 256 * i;         // 0..1023 = 32 rows x 32 uint2-cols
        int r = q & 31;
        int c2 = q >> 5;
        int row = row0 + r;
        uint2 v = make_uint2(0u, 0u);
        if (row < n) v = h2[(size_t)row * 32 + c2];
        int c = c2 << 2;
        xs[(c + 0) * 32 + r] = bflo(v.x);
        xs[(c + 1) * 32 + r] = bfhi(v.x);
        xs[(c + 2) * 32 + r] = bflo(v.y);
        xs[(c + 3) * 32 + r] = bfhi(v.y);
    }
    __syncthreads();

    int c4 = (t & 15) << 2;          // out col 0..60
    int r2 = (t >> 4) << 1;          // out row pair 0..30
    const float4* W4 = (const float4*)W2;   // row = 16 float4
    float acc[2][4] = {};
#pragma unroll 8
    for (int k = 0; k < 128; k++) {
        float2 xv = *(const float2*)&xs[k * 32 + r2];
        float4 wv = W4[k * 16 + (c4 >> 2)];
        acc[0][0] += xv.x * wv.x; acc[0][1] += xv.x * wv.y; acc[0][2] += xv.x * wv.z; acc[0][3] += xv.x * wv.w;
        acc[1][0] += xv.y * wv.x; acc[1][1] += xv.y * wv.y; acc[1][2] += xv.y * wv.z; acc[1][3] += xv.y * wv.w;
    }
#pragma unroll
    for (int i = 0; i < 2; i++) {
        int row = row0 + r2 + i;
        if (row < n)
            ((uint2*)xb2)[(size_t)row * 16 + (c4 >> 2)] =
                make_uint2(pack2bf(acc[i][0], acc[i][1]), pack2bf(acc[i][2], acc[i][3]));
    }
}

// ---- gather2 (+dinv, bias, PReLU) -> f fp32. Fixed-16 unrolled chunk -------
// Always-load (no etype branch): xb2 is 12.8 MB, cache-resident; cj=0 kills
// etype-0 and pad contributions.
__global__ __launch_bounds__(256) void k_g2(const int* __restrict__ order,
                                            const int* __restrict__ lens,
                                            const int2* __restrict__ ell,
                                            const unsigned* __restrict__ xb2,
                                            const float* __restrict__ dinv2,
                                            const float* __restrict__ b,
                                            const float* __restrict__ alpha,
                                            float* __restrict__ f, int n) {
    int t = threadIdx.x;
    int i = blockIdx.x * 16 + (t >> 4);
    if (i >= n) return;
    int g = t & 15;
    int d = order[i];
    int len = lens[d];
    const int2* row = ell + (size_t)d * ELL_CAP;
    const uint2* x2 = (const uint2*)xb2;

    float a0 = 0.f, a1 = 0.f, a2 = 0.f, a3 = 0.f;
    for (int k0 = 0; k0 < len; k0 += 16) {
        int kk = k0 + g;
        int2 ent = make_int2(0, 0);
        float cf = 0.f;
        if (kk < len) {
            ent = row[kk];
            cf = (float)(((unsigned)ent.x) >> 24) * dinv2[ent.x & 0xFFFFFF];
        }
#pragma unroll
        for (int j = 0; j < 16; j++) {
            int pej = __shfl(ent.x, j, 16);
            float cj = __shfl(cf, j, 16);
            uint2 q = x2[(size_t)(pej & 0xFFFFFF) * 16 + g];
            a0 += bflo(q.x) * cj; a1 += bfhi(q.x) * cj;
            a2 += bflo(q.y) * cj; a3 += bfhi(q.y) * cj;
        }
    }

    float di = dinv2[d];
    uint2 sq = x2[(size_t)d * 16 + g];
    int c4 = g << 2;
    float4 bv = *(const float4*)&b[c4];
    float4 av = *(const float4*)&alpha[c4];
    float f0 = di * (a0 + bflo(sq.x) * di) + bv.x; f0 = f0 >= 0.f ? f0 : av.x * f0;
    float f1 = di * (a1 + bfhi(sq.x) * di) + bv.y; f1 = f1 >= 0.f ? f1 : av.y * f1;
    float f2 = di * (a2 + bflo(sq.y) * di) + bv.z; f2 = f2 >= 0.f ? f2 : av.z * f2;
    float f3 = di * (a3 + bfhi(sq.y) * di) + bv.w; f3 = f3 >= 0.f ? f3 : av.w * f3;
    ((float4*)f)[(size_t)d * 16 + g] = make_float4(f0, f1, f2, f3);
}

__global__ __launch_bounds__(256) void k_half(const float* __restrict__ f,
                                              float* __restrict__ out, int half) {
    int idx = blockIdx.x * 256 + threadIdx.x;   // over half*16 float4s
    if (idx >= half * 16) return;
    int j = idx >> 4;
    int g = idx & 15;
    float4 a = ((const float4*)f)[(size_t)j * 16 + g];
    float4 c = ((const float4*)f)[(size_t)(j + half) * 16 + g];
    ((float4*)out)[idx] = make_float4(0.5f * (a.x + c.x), 0.5f * (a.y + c.y),
                                      0.5f * (a.z + c.z), 0.5f * (a.w + c.w));
}

extern "C" void kernel_launch(void* const* d_in, const int* in_sizes, int n_in,
                              void* d_out, int out_size, void* d_ws, size_t ws_size,
                              hipStream_t stream) {
    const float* x  = (const float*)d_in[0];
    const int*   ei = (const int*)d_in[1];
    const float* ew = (const float*)d_in[2];
    const int*   et = (const int*)d_in[3];
    const float* W1 = (const float*)d_in[4];
    const float* b1 = (const float*)d_in[5];
    const float* a1 = (const float*)d_in[6];
    const float* W2 = (const float*)d_in[7];
    const float* b2 = (const float*)d_in[8];
    const float* a2 = (const float*)d_in[9];

    const int N = in_sizes[0] / 128;   // 100000
    const int E = in_sizes[1] / 2;     // 1600000
    const int* src = ei;
    const int* dst = ei + E;

    // Workspace (4-byte words), ~118 MB:
    //   dinv1 N | dinv2 N | lens N | rank1 N | order N | cnt N | nbin 2080 |
    //   xb1 64N | h1b 64N | xb2 32N | ell 128N.   f aliases xb1 (dead after g1).
    float*    ws    = (float*)d_ws;
    float*    dinv1 = ws;
    float*    dinv2 = dinv1 + N;
    int*      lens  = (int*)(dinv2 + N);
    int*      rank1 = lens + N;
    int*      order = rank1 + N;
    int*      cnt   = order + N;
    int*      nbin  = cnt + N;                    // NREP*65 = 2080 ints
    unsigned* xb1   = (unsigned*)(nbin + NREP * 65);
    unsigned* h1b   = xb1 + (size_t)N * 64;
    unsigned* xb2   = h1b + (size_t)N * 64;
    int2*     ell   = (int2*)(xb2 + (size_t)N * 32);
    float*    f     = (float*)xb1;                // xb1 dead after k_g1

    const int half = N / 2;

    hipMemsetAsync(cnt, 0, ((size_t)N + NREP * 65) * sizeof(int), stream);

    k_gemm1<<<(N + 31) / 32, 256, 0, stream>>>(x, W1, xb1, N);

    k_ell<<<(E + 255) / 256, 256, 0, stream>>>(src, dst, et, ew, cnt, ell, E);

    k_dinv<<<(N + 15) / 16, 256, 0, stream>>>(cnt, ell, dinv1, dinv2,
                                              lens, rank1, nbin, N);
    k_offs<<<1, 256, 0, stream>>>(nbin);
    k_place<<<(N + 255) / 256, 256, 0, stream>>>(lens, rank1, nbin, order, N);

    k_g1<<<(N + 15) / 16, 256, 0, stream>>>(order, lens, ell, xb1, dinv1,
                                            b1, a1, h1b, N);

    k_gemm2b<<<(N + 31) / 32, 256, 0, stream>>>(h1b, W2, xb2, N);

    k_g2<<<(N + 15) / 16, 256, 0, stream>>>(order, lens, ell, xb2, dinv2,
                                            b2, a2, f, N);

    k_half<<<(half * 16 + 255) / 256, 256, 0, stream>>>(f, (float*)d_out, half);
}

// Round 10
// 447.301 us; speedup vs baseline: 1.0427x; 1.0219x over previous
//
#include <hip/hip_runtime.h>

// ---------------------------------------------------------------------------
// DoubleLayeredEncoder: 2-layer GCN + PReLU + half-sum. N=100k, E=1.6M.
// R10: shfl-free gathers. Each 16-lane subgroup broadcast-loads the ELL entry
// and dinv[src] (same-address wave load = 1 line fetch + HW broadcast; no
// ds_bpermute / lgkmcnt serialization), then loads its own 16B/8B slice of the
// feature row. Unroll-8 independent iterations -> 8 rows in flight/subgroup.
// Length-sort dropped (cost ~= divergence saved; natural order = coalesced
// h1b writes). Half-sum fused into g2 (pair j/j+half per 32 lanes, shfl_xor
// combine) -> f buffer + k_half eliminated. 7 dispatches.
//
// Pipeline: memset(cnt) -> gemm1 -> ell -> dinv -> g1 -> gemm2b -> g2h
// ---------------------------------------------------------------------------

#define ELL_CAP 64

__device__ __forceinline__ unsigned bf16rne(float x) {
    unsigned u = __float_as_uint(x);
    return (u + 0x7FFFu + ((u >> 16) & 1u)) >> 16;
}
__device__ __forceinline__ unsigned pack2bf(float a, float b) {
    return bf16rne(a) | (bf16rne(b) << 16);
}
__device__ __forceinline__ float bflo(unsigned u) { return __uint_as_float(u << 16); }
__device__ __forceinline__ float bfhi(unsigned u) { return __uint_as_float(u & 0xFFFF0000u); }

// ---- ELL build: 1 edge/thread (measured random-line-touch floor) -----------
__global__ __launch_bounds__(256) void k_ell(const int* __restrict__ src,
                                             const int* __restrict__ dst,
                                             const int* __restrict__ et,
                                             const float* __restrict__ w,
                                             int* __restrict__ cnt,
                                             int2* __restrict__ ell, int E) {
    int e = blockIdx.x * 256 + threadIdx.x;
    if (e >= E) return;
    int d = dst[e];
    int pos = atomicAdd(&cnt[d], 1);
    if (pos < ELL_CAP)
        ell[(size_t)d * ELL_CAP + pos] =
            make_int2(src[e] | (et[e] << 24), __float_as_int(w[e]));
}

// ---- degrees + rsqrt + len, 16 lanes/node ----------------------------------
__global__ __launch_bounds__(256) void k_dinv(const int* __restrict__ cnt,
                                              const int2* __restrict__ ell,
                                              float* __restrict__ dinv1,
                                              float* __restrict__ dinv2,
                                              int* __restrict__ lens, int n) {
    int t = threadIdx.x;
    int d = blockIdx.x * 16 + (t >> 4);
    int g = t & 15;
    float s1 = 0.f, s2 = 0.f;
    int len = 0;
    if (d < n) {
        len = min(cnt[d], ELL_CAP);
        const int2* row = ell + (size_t)d * ELL_CAP;
        for (int kk = g; kk < len; kk += 16) {
            int2 e = row[kk];
            s1 += __int_as_float(e.y);
            s2 += (float)(((unsigned)e.x) >> 24);
        }
    }
#pragma unroll
    for (int o = 8; o >= 1; o >>= 1) {
        s1 += __shfl_xor(s1, o, 16);
        s2 += __shfl_xor(s2, o, 16);
    }
    if (d < n && g == 0) {
        dinv1[d] = rsqrtf(1.0f + s1);
        dinv2[d] = rsqrtf(1.0f + s2);
        lens[d] = len;
    }
}

// ---- gemm1: xb1 = bf16(x @ W1) UNSCALED. 32 rows/block, W from L2 ----------
__global__ __launch_bounds__(256) void k_gemm1(const float* __restrict__ x,
                                               const float* __restrict__ W,
                                               unsigned* __restrict__ xb1, int n) {
    __shared__ float xs[128 * 32];   // [k][r], lane-fast row map (conflict-free)
    int t = threadIdx.x;
    int row0 = blockIdx.x * 32;
    const float4* x4 = (const float4*)x;
#pragma unroll
    for (int i = 0; i < 4; i++) {
        int q = t + 256 * i;
        int r = q & 31;
        int c4 = (q >> 5) << 2;
        int row = row0 + r;
        float4 v = make_float4(0.f, 0.f, 0.f, 0.f);
        if (row < n) v = x4[row * 32 + (c4 >> 2)];
        xs[(c4 + 0) * 32 + r] = v.x;
        xs[(c4 + 1) * 32 + r] = v.y;
        xs[(c4 + 2) * 32 + r] = v.z;
        xs[(c4 + 3) * 32 + r] = v.w;
    }
    __syncthreads();

    int c4 = (t & 31) << 2;
    int r4 = (t >> 5) << 2;
    const float4* W4 = (const float4*)W;
    float acc[4][4] = {};
#pragma unroll 8
    for (int k = 0; k < 128; k++) {
        float4 xv = *(const float4*)&xs[k * 32 + r4];
        float4 wv = W4[k * 32 + (c4 >> 2)];
        acc[0][0] += xv.x * wv.x; acc[0][1] += xv.x * wv.y; acc[0][2] += xv.x * wv.z; acc[0][3] += xv.x * wv.w;
        acc[1][0] += xv.y * wv.x; acc[1][1] += xv.y * wv.y; acc[1][2] += xv.y * wv.z; acc[1][3] += xv.y * wv.w;
        acc[2][0] += xv.z * wv.x; acc[2][1] += xv.z * wv.y; acc[2][2] += xv.z * wv.z; acc[2][3] += xv.z * wv.w;
        acc[3][0] += xv.w * wv.x; acc[3][1] += xv.w * wv.y; acc[3][2] += xv.w * wv.z; acc[3][3] += xv.w * wv.w;
    }
#pragma unroll
    for (int i = 0; i < 4; i++) {
        int row = row0 + r4 + i;
        if (row < n) {
            uint2 o = make_uint2(pack2bf(acc[i][0], acc[i][1]),
                                 pack2bf(acc[i][2], acc[i][3]));
            ((uint2*)xb1)[row * 32 + (c4 >> 2)] = o;
        }
    }
}

// ---- gather1 (+dinv, bias, PReLU) -> h1 bf16. 16 lanes x 8ch, shfl-free ----
__global__ __launch_bounds__(256) void k_g1(const int* __restrict__ lens,
                                            const int2* __restrict__ ell,
                                            const unsigned* __restrict__ xb1,
                                            const float* __restrict__ dinv1,
                                            const float* __restrict__ b,
                                            const float* __restrict__ alpha,
                                            unsigned* __restrict__ h1b, int n) {
    int t = threadIdx.x;
    int d = blockIdx.x * 16 + (t >> 4);
    if (d >= n) return;
    int g = t & 15;
    int len = lens[d];
    const int2* row = ell + (size_t)d * ELL_CAP;
    const uint4* x4 = (const uint4*)xb1;

    float a0 = 0.f, a1 = 0.f, a2 = 0.f, a3 = 0.f;
    float a4 = 0.f, a5 = 0.f, a6 = 0.f, a7 = 0.f;
    for (int k0 = 0; k0 < len; k0 += 8) {
#pragma unroll
        for (int j = 0; j < 8; j++) {
            int kk = min(k0 + j, len - 1);
            int2 ent = row[kk];                     // same addr across subgroup
            int s = ent.x & 0xFFFFFF;
            float cf = (k0 + j < len)
                     ? __int_as_float(ent.y) * dinv1[s]   // w*dinv1[src], broadcast
                     : 0.f;
            uint4 q = x4[(size_t)s * 16 + g];
            a0 += bflo(q.x) * cf; a1 += bfhi(q.x) * cf;
            a2 += bflo(q.y) * cf; a3 += bfhi(q.y) * cf;
            a4 += bflo(q.z) * cf; a5 += bfhi(q.z) * cf;
            a6 += bflo(q.w) * cf; a7 += bfhi(q.w) * cf;
        }
    }

    float di = dinv1[d];
    uint4 sq = x4[(size_t)d * 16 + g];
    int c8 = g << 3;
    float4 blo = *(const float4*)&b[c8], bhi = *(const float4*)&b[c8 + 4];
    float4 alo = *(const float4*)&alpha[c8], ahi = *(const float4*)&alpha[c8 + 4];
    float v0 = di * (a0 + bflo(sq.x) * di) + blo.x; v0 = v0 >= 0.f ? v0 : alo.x * v0;
    float v1 = di * (a1 + bfhi(sq.x) * di) + blo.y; v1 = v1 >= 0.f ? v1 : alo.y * v1;
    float v2 = di * (a2 + bflo(sq.y) * di) + blo.z; v2 = v2 >= 0.f ? v2 : alo.z * v2;
    float v3 = di * (a3 + bfhi(sq.y) * di) + blo.w; v3 = v3 >= 0.f ? v3 : alo.w * v3;
    float v4 = di * (a4 + bflo(sq.z) * di) + bhi.x; v4 = v4 >= 0.f ? v4 : ahi.x * v4;
    float v5 = di * (a5 + bfhi(sq.z) * di) + bhi.y; v5 = v5 >= 0.f ? v5 : ahi.y * v5;
    float v6 = di * (a6 + bflo(sq.w) * di) + bhi.z; v6 = v6 >= 0.f ? v6 : ahi.z * v6;
    float v7 = di * (a7 + bfhi(sq.w) * di) + bhi.w; v7 = v7 >= 0.f ? v7 : ahi.w * v7;
    ((uint4*)h1b)[(size_t)d * 16 + g] =
        make_uint4(pack2bf(v0, v1), pack2bf(v2, v3), pack2bf(v4, v5), pack2bf(v6, v7));
}

// ---- gemm2b: xb2 = bf16(h1b @ W2) UNSCALED. 32 rows/block, 2x4 acc ---------
__global__ __launch_bounds__(256) void k_gemm2b(const unsigned* __restrict__ h1b,
                                                const float* __restrict__ W2,
                                                unsigned* __restrict__ xb2, int n) {
    __shared__ float xs[128 * 32];   // [k][r], 16 KB
    int t = threadIdx.x;
    int row0 = blockIdx.x * 32;
    const uint2* h2 = (const uint2*)h1b;   // row = 32 uint2 (128 bf16)
#pragma unroll
    for (int i = 0; i < 4; i++) {
        int q = t + 256 * i;         // 0..1023 = 32 rows x 32 uint2-cols
        int r = q & 31;
        int c2 = q >> 5;
        int row = row0 + r;
        uint2 v = make_uint2(0u, 0u);
        if (row < n) v = h2[(size_t)row * 32 + c2];
        int c = c2 << 2;
        xs[(c + 0) * 32 + r] = bflo(v.x);
        xs[(c + 1) * 32 + r] = bfhi(v.x);
        xs[(c + 2) * 32 + r] = bflo(v.y);
        xs[(c + 3) * 32 + r] = bfhi(v.y);
    }
    __syncthreads();

    int c4 = (t & 15) << 2;          // out col 0..60
    int r2 = (t >> 4) << 1;          // out row pair 0..30
    const float4* W4 = (const float4*)W2;   // row = 16 float4
    float acc[2][4] = {};
#pragma unroll 8
    for (int k = 0; k < 128; k++) {
        float2 xv = *(const float2*)&xs[k * 32 + r2];
        float4 wv = W4[k * 16 + (c4 >> 2)];
        acc[0][0] += xv.x * wv.x; acc[0][1] += xv.x * wv.y; acc[0][2] += xv.x * wv.z; acc[0][3] += xv.x * wv.w;
        acc[1][0] += xv.y * wv.x; acc[1][1] += xv.y * wv.y; acc[1][2] += xv.y * wv.z; acc[1][3] += xv.y * wv.w;
    }
#pragma unroll
    for (int i = 0; i < 2; i++) {
        int row = row0 + r2 + i;
        if (row < n)
            ((uint2*)xb2)[(size_t)row * 16 + (c4 >> 2)] =
                make_uint2(pack2bf(acc[i][0], acc[i][1]), pack2bf(acc[i][2], acc[i][3]));
    }
}

// ---- gather2 (+dinv, bias, PReLU) + half-sum, shfl-free, pair-fused --------
// 8 pairs/block; 32 lanes per pair: lanes 0-15 node j, 16-31 node j+half.
__global__ __launch_bounds__(256) void k_g2h(const int* __restrict__ lens,
                                             const int2* __restrict__ ell,
                                             const unsigned* __restrict__ xb2,
                                             const float* __restrict__ dinv2,
                                             const float* __restrict__ b,
                                             const float* __restrict__ alpha,
                                             float* __restrict__ out, int half) {
    int t = threadIdx.x;
    int pair = blockIdx.x * 8 + (t >> 5);
    if (pair >= half) return;
    int u = t & 31;
    int sub = u >> 4;                 // 0: node j, 1: node j+half
    int g = u & 15;
    int d = pair + sub * half;
    int len = lens[d];
    const int2* row = ell + (size_t)d * ELL_CAP;
    const uint2* x2 = (const uint2*)xb2;

    float a0 = 0.f, a1 = 0.f, a2 = 0.f, a3 = 0.f;
    for (int k0 = 0; k0 < len; k0 += 8) {
#pragma unroll
        for (int j = 0; j < 8; j++) {
            int kk = min(k0 + j, len - 1);
            int2 ent = row[kk];                     // broadcast within subgroup
            int s = ent.x & 0xFFFFFF;
            float cf = (k0 + j < len)
                     ? (float)(((unsigned)ent.x) >> 24) * dinv2[s]
                     : 0.f;
            uint2 q = x2[(size_t)s * 16 + g];
            a0 += bflo(q.x) * cf; a1 += bfhi(q.x) * cf;
            a2 += bflo(q.y) * cf; a3 += bfhi(q.y) * cf;
        }
    }

    float di = dinv2[d];
    uint2 sq = x2[(size_t)d * 16 + g];
    int c4 = g << 2;
    float4 bv = *(const float4*)&b[c4];
    float4 av = *(const float4*)&alpha[c4];
    float f0 = di * (a0 + bflo(sq.x) * di) + bv.x; f0 = f0 >= 0.f ? f0 : av.x * f0;
    float f1 = di * (a1 + bfhi(sq.x) * di) + bv.y; f1 = f1 >= 0.f ? f1 : av.y * f1;
    float f2 = di * (a2 + bflo(sq.y) * di) + bv.z; f2 = f2 >= 0.f ? f2 : av.z * f2;
    float f3 = di * (a3 + bfhi(sq.y) * di) + bv.w; f3 = f3 >= 0.f ? f3 : av.w * f3;

    // combine j with j+half: exchange across the 16-lane boundary
    float p0 = __shfl_xor(f0, 16, 32);
    float p1 = __shfl_xor(f1, 16, 32);
    float p2 = __shfl_xor(f2, 16, 32);
    float p3 = __shfl_xor(f3, 16, 32);
    if (sub == 0)
        ((float4*)out)[(size_t)pair * 16 + g] =
            make_float4(0.5f * (f0 + p0), 0.5f * (f1 + p1),
                        0.5f * (f2 + p2), 0.5f * (f3 + p3));
}

extern "C" void kernel_launch(void* const* d_in, const int* in_sizes, int n_in,
                              void* d_out, int out_size, void* d_ws, size_t ws_size,
                              hipStream_t stream) {
    const float* x  = (const float*)d_in[0];
    const int*   ei = (const int*)d_in[1];
    const float* ew = (const float*)d_in[2];
    const int*   et = (const int*)d_in[3];
    const float* W1 = (const float*)d_in[4];
    const float* b1 = (const float*)d_in[5];
    const float* a1 = (const float*)d_in[6];
    const float* W2 = (const float*)d_in[7];
    const float* b2 = (const float*)d_in[8];
    const float* a2 = (const float*)d_in[9];

    const int N = in_sizes[0] / 128;   // 100000
    const int E = in_sizes[1] / 2;     // 1600000
    const int* src = ei;
    const int* dst = ei + E;

    // Workspace (4-byte words), ~117 MB:
    //   dinv1 N | dinv2 N | lens N | cnt N | xb1 64N | h1b 64N | xb2 32N | ell 128N
    float*    ws    = (float*)d_ws;
    float*    dinv1 = ws;
    float*    dinv2 = dinv1 + N;
    int*      lens  = (int*)(dinv2 + N);
    int*      cnt   = lens + N;
    unsigned* xb1   = (unsigned*)(cnt + N);
    unsigned* h1b   = xb1 + (size_t)N * 64;
    unsigned* xb2   = h1b + (size_t)N * 64;
    int2*     ell   = (int2*)(xb2 + (size_t)N * 32);

    const int half = N / 2;

    hipMemsetAsync(cnt, 0, (size_t)N * sizeof(int), stream);

    k_gemm1<<<(N + 31) / 32, 256, 0, stream>>>(x, W1, xb1, N);

    k_ell<<<(E + 255) / 256, 256, 0, stream>>>(src, dst, et, ew, cnt, ell, E);

    k_dinv<<<(N + 15) / 16, 256, 0, stream>>>(cnt, ell, dinv1, dinv2, lens, N);

    k_g1<<<(N + 15) / 16, 256, 0, stream>>>(lens, ell, xb1, dinv1, b1, a1, h1b, N);

    k_gemm2b<<<(N + 31) / 32, 256, 0, stream>>>(h1b, W2, xb2, N);

    k_g2h<<<(half + 7) / 8, 256, 0, stream>>>(lens, ell, xb2, dinv2, b2, a2,
                                              (float*)d_out, half);
}